// Round 9
// baseline (589.763 us; speedup 1.0000x reference)
//
#include <hip/hip_runtime.h>

// KAN layer as one fused fp16 MFMA GEMM:
//   out[b,i] = sum_j [ neg*bw*pw + pos*bw + sum_k basis[b,j,k]*sw[i,j]*sc[i,j,k] ]
// R9: FRAGMENT-ORDER WORKSPACE, REGISTER-DIRECT GEMM.
//   Every LDS-staged variant (R2-R5, R8) pinned at 62-77us: the compiler
//   inserts vmcnt(0) before any ds_read dependent on global_load_lds (m131/
//   m135), exposing full memory latency per 32-K chunk. R6 (reg-direct from
//   row-major) died on scattered 16B/lane loads. Fix: prep writes A and B in
//   MFMA-FRAGMENT ORDER [tile16][k_chunk32][lane][8], so a fragment load is
//   ONE coalesced global_load_dwordx4 (addr = base + 16*lane). K-loop =
//   loads->VGPR + MFMA, no LDS, no barriers; compiler emits precise per-reg
//   vmcnt(N); 2-deep register prefetch + 8 waves/CU hides latency.
// A_frag 46.1 MB, B_frag 11.5 MB (57.7 MB ws). Grid (16,4,11), 128x128 tile,
// wave-tile 32x128, splitK=11 + f32 atomics (R4-measured acceptable).

typedef _Float16 half_t;
typedef __attribute__((ext_vector_type(8))) _Float16 half8;
typedef __attribute__((ext_vector_type(4))) float floatx4;

#define B_DIM   2048
#define J_DIM   512
#define O_DIM   512
#define SLOTS   22
#define K_TOT   (J_DIM * SLOTS)      // 11264 halves per logical row
#define KC_TOT  (K_TOT / 32)         // 352 k-chunks
#define MTILE   128
#define NTILE   128
#define KSPLIT  11
#define KCH     (KC_TOT / KSPLIT)    // 32 chunks per split
#define ZERO_BLKS 64
#define BPREP_BLKS 512               // 32 n_tiles x 16 j-slices
#define APREP_BLKS 2048              // 128 m_tiles x 16 j-slices

// ---------------------------------------------------------------------------
// Quartic B-spline local basis, uniform knots g_i = -1.5 + i*(3.125/24).
// (Reference quirk: linspace(-1.5,1.625,25) -> spacing 3.125/24, NOT 0.125.)
// m in [3,19]; window k = m-4..m, entries with k<0 dropped.
__device__ __forceinline__ void bspline5(float xc, int& k0, float Nv[5]) {
    const float invS = 7.68f;              // 24/3.125 (exact ratio)
    float u = (xc + 1.5f) * invS;
    int m = (int)u;
    m = min(max(m, 3), 19);
    k0 = m - 4;
    Nv[0] = 1.f; Nv[1] = 0.f; Nv[2] = 0.f; Nv[3] = 0.f; Nv[4] = 0.f;
#pragma unroll
    for (int d = 1; d <= 4; ++d) {
        float nw[5];
        float inv_d = 1.0f / (float)d;
#pragma unroll
        for (int r = 0; r < 5; ++r) {
            if (r > d) { nw[r] = 0.f; continue; }
            float kk = (float)(m - d + r);
            float acc = 0.f;
            if (r >= 1) acc += (u - kk) * Nv[r - 1];
            if (r < d)  acc += (kk + (float)(d + 1) - u) * Nv[r];
            nw[r] = acc * inv_d;
        }
#pragma unroll
        for (int r = 0; r < 5; ++r) Nv[r] = nw[r];
    }
}

// ---------------------------------------------------------------------------
// Fragment-order index: element (row, kk) of a logical [rows x 11264] matrix
// lives at half-index ((tile*352 + kk/32)*64 + lane)*8 + kk%8, where
// tile = row/16, lane = ((kk>>3)&3)*16 + (row&15).  A wave's 16x16x32 MFMA
// fragment for (tile, chunk) is then 64 lanes x 16 B contiguous.
__device__ __forceinline__ int frag_lds_idx(int kk, int r) {
    return ((kk >> 5) * 64 + ((kk >> 3) & 3) * 16 + r) * 8 + (kk & 7);
}

// Fused prep: [0,64) zero out; [64,576) B-frag rows; [576,2624) A-frag rows.
// Each frag block = (tile of 16 rows) x (j-slice of 32 j's) = 22 k-chunks:
// scatter 512 records into LDS in fragment order, then one contiguous
// 22.5 KB coalesced copy to the workspace.
__global__ __launch_bounds__(256) void prep_all(const float* __restrict__ x,
                                                const float* __restrict__ pw,
                                                const float* __restrict__ bw,
                                                const float* __restrict__ sw,
                                                const float* __restrict__ sc,
                                                half_t* __restrict__ Af,
                                                half_t* __restrict__ Bf,
                                                float* __restrict__ out) {
    __shared__ half_t rec[SLOTS * 512];   // 22 chunks * 64 lanes * 8 = 22528 B
    int bid = blockIdx.x;
    int t = threadIdx.x;

    if (bid < ZERO_BLKS) {
        float4* o = (float4*)out;
        int base = bid * 4096;
#pragma unroll
        for (int i = 0; i < 16; ++i)
            o[base + i * 256 + t] = make_float4(0.f, 0.f, 0.f, 0.f);
        return;
    }

    bool isB = bid < ZERO_BLKS + BPREP_BLKS;
    int idx = isB ? (bid - ZERO_BLKS) : (bid - ZERO_BLKS - BPREP_BLKS);
    int tile = idx >> 4;     // n_tile (0..31) or m_tile (0..127)
    int js   = idx & 15;     // j-slice: j in [js*32, js*32+32)

#pragma unroll
    for (int pp = 0; pp < 2; ++pp) {
        int pi = t + pp * 256;          // 0..511
        int r  = pi & 15;               // row within tile
        int jl = pi >> 4;               // 0..31
        int j  = js * 32 + jl;
        int row = tile * 16 + r;
        int kb = jl * SLOTS;            // local kk base (0..682)
        if (isB) {
            size_t ij = (size_t)row * J_DIM + j;
            float s = sw[ij], b = bw[ij], p = pw[ij];
            const float4* c4p = (const float4*)(sc + ij * 20);
#pragma unroll
            for (int v = 0; v < 5; ++v) {
                float4 c4 = c4p[v];
                rec[frag_lds_idx(kb + v * 4 + 0, r)] = (half_t)(s * c4.x);
                rec[frag_lds_idx(kb + v * 4 + 1, r)] = (half_t)(s * c4.y);
                rec[frag_lds_idx(kb + v * 4 + 2, r)] = (half_t)(s * c4.z);
                rec[frag_lds_idx(kb + v * 4 + 3, r)] = (half_t)(s * c4.w);
            }
            rec[frag_lds_idx(kb + 20, r)] = (half_t)(b * p);
            rec[frag_lds_idx(kb + 21, r)] = (half_t)b;
        } else {
            float xv = x[(size_t)row * J_DIM + j];
            float xc = fminf(fmaxf(xv, -1.f), 1.f);
            float pos = fmaxf(xc, 0.f);
            float neg = xc - pos;
            int k0; float Nv[5];
            bspline5(xc, k0, Nv);
            float vals[20];
#pragma unroll
            for (int s = 0; s < 20; ++s) vals[s] = 0.f;
#pragma unroll
            for (int rr = 0; rr < 5; ++rr) {
                int k = k0 + rr;
                if (k >= 0) vals[k] = Nv[rr];   // k<=19 guaranteed (k0<=15)
            }
#pragma unroll
            for (int s = 0; s < 20; ++s)
                rec[frag_lds_idx(kb + s, r)] = (half_t)vals[s];
            rec[frag_lds_idx(kb + 20, r)] = (half_t)neg;
            rec[frag_lds_idx(kb + 21, r)] = (half_t)pos;
        }
    }
    __syncthreads();
    const uint4* src = (const uint4*)rec;
    half_t* base = isB ? Bf : Af;
    uint4* dst = (uint4*)base + ((size_t)tile * KC_TOT + js * SLOTS) * 64;
#pragma unroll
    for (int pp = 0; pp < 6; ++pp) {                 // 1408 uint4, 256 thr
        int i2 = t + pp * 256;
        if (i2 < SLOTS * 64) dst[i2] = src[i2];
    }
}

// ---------------------------------------------------------------------------
// Register-direct GEMM. Grid (16,4,11), 256 thr = 4 waves, block tile 128x128,
// wave w owns rows [m0+w*32, +32) x all 128 cols (m_tiles mt0, mt0+1;
// n_tiles nt0..nt0+7 — B-frag loads identical across waves -> L1 hits).
// Per chunk per wave: 2 A-frag + 8 B-frag coalesced global_load_dwordx4,
// 16 MFMA. 2-deep register prefetch; no LDS, no barriers — compiler emits
// precise vmcnt(N) per fragment register.
__global__ __launch_bounds__(256, 2) void gemm_f16(const half_t* __restrict__ Af,
                                                   const half_t* __restrict__ Bf,
                                                   float* __restrict__ out) {
    int m0 = blockIdx.x * MTILE;
    int n0 = blockIdx.y * NTILE;
    int kc0 = blockIdx.z * KCH;

    int t = threadIdx.x;
    int w = t >> 6, l = t & 63;
    int q = l >> 4, fr = l & 15;

    int mt0 = (m0 >> 4) + w * 2;
    int nt0 = (n0 >> 4);

    const half8* pa = (const half8*)Af + ((size_t)mt0 * KC_TOT + kc0) * 64 + l;
    const half8* pb = (const half8*)Bf + ((size_t)nt0 * KC_TOT + kc0) * 64 + l;
    const size_t ts = (size_t)KC_TOT * 64;   // tile stride in half8 units

    floatx4 acc[2][8] = {};
    half8 a[2][2], b[2][8];

#define LOADSET(s, c)                                                         \
    {                                                                         \
        _Pragma("unroll")                                                     \
        for (int mt = 0; mt < 2; ++mt) a[s][mt] = pa[mt * ts + (c) * 64];     \
        _Pragma("unroll")                                                     \
        for (int nt = 0; nt < 8; ++nt) b[s][nt] = pb[nt * ts + (c) * 64];     \
    }

    LOADSET(0, 0)
    LOADSET(1, 1)

    int cur = 0;
#pragma unroll 1
    for (int c = 0; c < KCH; ++c) {
#pragma unroll
        for (int mt = 0; mt < 2; ++mt)
#pragma unroll
            for (int nt = 0; nt < 8; ++nt)
                acc[mt][nt] = __builtin_amdgcn_mfma_f32_16x16x32_f16(
                    a[cur][mt], b[cur][nt], acc[mt][nt], 0, 0, 0);
        if (c + 2 < KCH) LOADSET(cur, c + 2)
        cur ^= 1;
    }
#undef LOADSET

    // epilogue: C/D layout col = lane&15, row = (lane>>4)*4 + reg (m89-verified)
#pragma unroll
    for (int mt = 0; mt < 2; ++mt)
#pragma unroll
        for (int nt = 0; nt < 8; ++nt) {
            int rr = m0 + w * 32 + mt * 16 + q * 4;
            int cc = n0 + nt * 16 + fr;
#pragma unroll
            for (int r = 0; r < 4; ++r)
                atomicAdd(out + (size_t)(rr + r) * O_DIM + cc, acc[mt][nt][r]);
        }
}

// ---------------------------------------------------------------------------
// Zero-workspace fallback (only if ws_size too small): correct but slow.
__global__ __launch_bounds__(256) void kan_fallback(const float* __restrict__ x,
                                                    const float* __restrict__ pw,
                                                    const float* __restrict__ bw,
                                                    const float* __restrict__ sw,
                                                    const float* __restrict__ sc,
                                                    float* __restrict__ out) {
    __shared__ float s_neg[J_DIM], s_pos[J_DIM], s_bas[J_DIM][5];
    __shared__ int s_k0[J_DIM];
    int b = blockIdx.x;
    int t = threadIdx.x;
#pragma unroll
    for (int jj = 0; jj < 2; ++jj) {
        int j = t + jj * 256;
        float xv = x[(size_t)b * J_DIM + j];
        float xc = fminf(fmaxf(xv, -1.f), 1.f);
        float pos = fmaxf(xc, 0.f);
        s_pos[j] = pos;
        s_neg[j] = xc - pos;
        int k0; float Nv[5];
        bspline5(xc, k0, Nv);
        s_k0[j] = k0;
#pragma unroll
        for (int r = 0; r < 5; ++r) s_bas[j][r] = Nv[r];
    }
    __syncthreads();
    for (int i = t; i < O_DIM; i += 256) {
        float acc = 0.f;
        for (int j = 0; j < J_DIM; ++j) {
            size_t ij = (size_t)i * J_DIM + j;
            float bwv = bw[ij];
            acc += bwv * (pw[ij] * s_neg[j] + s_pos[j]);
            int k0 = s_k0[j];
            const float* cp = sc + ij * 20;
            float sp = 0.f;
#pragma unroll
            for (int r = 0; r < 5; ++r) {
                int k = k0 + r;
                if (k >= 0) sp += s_bas[j][r] * cp[k];
            }
            acc += sw[ij] * sp;
        }
        out[(size_t)b * O_DIM + i] = acc;
    }
}

// ---------------------------------------------------------------------------
extern "C" void kernel_launch(void* const* d_in, const int* in_sizes, int n_in,
                              void* d_out, int out_size, void* d_ws, size_t ws_size,
                              hipStream_t stream) {
    const float* x  = (const float*)d_in[0];
    const float* pw = (const float*)d_in[1];
    const float* bw = (const float*)d_in[2];
    const float* sw = (const float*)d_in[3];
    const float* sc = (const float*)d_in[4];
    float* out = (float*)d_out;

    const size_t ws_needed = (size_t)(B_DIM + O_DIM) * K_TOT * sizeof(half_t); // 57.7 MB
    if (ws_size < ws_needed) {
        kan_fallback<<<B_DIM, 256, 0, stream>>>(x, pw, bw, sw, sc, out);
        return;
    }

    half_t* Af = (half_t*)d_ws;                         // fragment-order A
    half_t* Bf = Af + (size_t)B_DIM * K_TOT;            // fragment-order B

    prep_all<<<ZERO_BLKS + BPREP_BLKS + APREP_BLKS, 256, 0, stream>>>(
        x, pw, bw, sw, sc, Af, Bf, out);
    dim3 g(B_DIM / MTILE, O_DIM / NTILE, KSPLIT);       // (16, 4, 11)
    gemm_f16<<<g, 256, 0, stream>>>(Af, Bf, out);
}